// Round 10
// baseline (106.361 us; speedup 1.0000x reference)
//
#include <hip/hip_runtime.h>
#include <hip/hip_bf16.h>

// VectorQuantizer on MI355X — Round 17: amortize LDS reads (64 px/wave).
// z: [32, 64, 64, 64] fp32 (B,C,H,W), emb: [1024, 64] fp32.
// out: z_q [32,64,64,64] fp32 (8388608) then loss (1 float).
//
// R16 post-mortem: barrier-free loop -> 104.8 best. Main-loop model:
// 3 ds_read_b128 per g feed only 4 MFMAs (2 px-groups) -> LDS traffic
// 3KB x 64g x 16w ~= 3.1MB/CU ~= 12-15 us at measured 85B/cy — the
// widest pipe (MFMA ~2, VALU ~3.4, z-HBM ~5.5). LDS-BW-bound. R17:
// wave owns 64 px (bfr[4][2] = 32 VGPR): same 3 reads feed 8 MFMAs ->
// LDS/CU halves to ~1.6MB (~6-7us). 512-thr blocks (8 waves), grid 256
// = 1 block/CU (132KB LDS caps anyway). launch_bounds(512,2) = honest
// <=256-VGPR budget (R15 lesson: never force-squeeze; live ~90).
// Occupancy will read ~25% — expected; loop hides latency via ILP
// (4 indep MFMA chains/g, unroll-2 -> 6 in-flight ds_reads), not TLP.
// Tells: WRITE ~32.8MB (no spill), VGPR 80-110, conflicts ~0.

#define NELEM 8388608
#define NBLK  256

typedef short sv8 __attribute__((ext_vector_type(8)));
typedef float fv4 __attribute__((ext_vector_type(4)));
typedef int   iv4 __attribute__((ext_vector_type(4)));
typedef unsigned int uint32;

__device__ __forceinline__ uint32 pack2bf(float a, float b) {
    __hip_bfloat162 h = __float22bfloat162_rn(make_float2(a, b));
    union { __hip_bfloat162 h2; uint32 u; } cvt;
    cvt.h2 = h;
    return cvt.u;             // low 16 = a, high 16 = b
}

__device__ __forceinline__ uint32 umax(uint32 a, uint32 b) { return a > b ? a : b; }

// ---- prep: codebook -> bf16 A-frags (fragment order) + e2n = 1-0.5||e||^2.
//      Also zeroes the loss slot (stream-ordered before vq every replay).
__global__ __launch_bounds__(256) void prep_kernel(
        const float* __restrict__ embf,
        iv4* __restrict__ fragws,            // 8192 units of 16B
        float* __restrict__ e2n,             // 1024 floats
        float* __restrict__ out_loss) {
    if (blockIdx.x == 0 && threadIdx.x == 0) out_loss[0] = 0.0f;
    const int t = blockIdx.x * 256 + threadIdx.x;   // 0..4095
    const int g = t >> 6, l = t & 63;
    const int code = g * 16 + (l & 15);
    const int q    = l >> 4;
    float s2 = 0.0f;
#pragma unroll
    for (int kc = 0; kc < 2; ++kc) {
        fv4 u0 = ((const fv4*)embf)[code * 16 + kc * 8 + q * 2 + 0];
        fv4 u1 = ((const fv4*)embf)[code * 16 + kc * 8 + q * 2 + 1];
        s2 += u0[0]*u0[0] + u0[1]*u0[1] + u0[2]*u0[2] + u0[3]*u0[3]
            + u1[0]*u1[0] + u1[1]*u1[1] + u1[2]*u1[2] + u1[3]*u1[3];
        iv4 pv = { (int)pack2bf(u0[0], u0[1]), (int)pack2bf(u0[2], u0[3]),
                   (int)pack2bf(u1[0], u1[1]), (int)pack2bf(u1[2], u1[3]) };
        fragws[(g * 2 + kc) * 64 + l] = pv;
    }
    s2 += __shfl_xor(s2, 16);
    s2 += __shfl_xor(s2, 32);                // full ||e_code||^2
    if (q == 0) e2n[code] = 1.0f - 0.5f * s2;
}

__global__ __launch_bounds__(512, 2) void vq_kernel(
        const float* __restrict__ z,
        const float* __restrict__ embf,
        const iv4* __restrict__ fragws,
        const float* __restrict__ e2n,
        float* __restrict__ out) {
    __shared__ iv4   afr_lds[128 * 64];      // 128 KB  A-frags [g*2+kc][lane]
    __shared__ float e2nl[1024];             //   4 KB  1-0.5||e||^2
    __shared__ float lred[8];

    const int tid   = threadIdx.x;
    const int blk   = blockIdx.x;
    const int batch = blk >> 3;
    const int hw0   = (blk & 7) << 9;        // 512 pixels per block
    const int zb    = batch * 262144;        // + c*4096 + px

    const int wv   = tid >> 6;               // 0..7
    const int lane = tid & 63;
    const int q    = lane >> 4;
    const int mcol = lane & 15;
    const int pxb  = hw0 + wv * 64;          // wave's 64 pixels

    // ---- own B-frags (4 px-groups of 16) in registers + ||z||^2.
    // Issue HBM z-loads first; codebook LDS-stage overlaps their latency.
    sv8   bfr[4][2];
    float zn[4];
#pragma unroll
    for (int j = 0; j < 4; ++j) {
        const int col = pxb + j * 16 + mcol;
        float sq = 0.0f;
#pragma unroll
        for (int kc = 0; kc < 2; ++kc) {
            uint32 pk[4];
#pragma unroll
            for (int jj = 0; jj < 4; ++jj) {
                float f0 = z[zb + (kc * 32 + q * 8 + jj * 2 + 0) * 4096 + col];
                float f1 = z[zb + (kc * 32 + q * 8 + jj * 2 + 1) * 4096 + col];
                sq += f0 * f0 + f1 * f1;
                pk[jj] = pack2bf(f0, f1);
            }
            iv4 v = { (int)pk[0], (int)pk[1], (int)pk[2], (int)pk[3] };
            bfr[j][kc] = *(sv8*)&v;
        }
        sq += __shfl_xor(sq, 16);
        sq += __shfl_xor(sq, 32);            // full ||z_px||^2
        zn[j] = sq;
    }

    // ---- stage codebook frags + e2n to LDS (L2-hot, coalesced)
#pragma unroll
    for (int i = 0; i < 16; ++i)
        afr_lds[i * 512 + tid] = fragws[i * 512 + tid];
    e2nl[tid]       = e2n[tid];
    e2nl[tid + 512] = e2n[tid + 512];
    __syncthreads();

    // ---- main loop: 64 code-groups, BARRIER-FREE, per-wave independent.
    // 3 ds_read_b128 per g feed 8 MFMAs (4 independent acc chains).
    uint32 best[4] = {0u, 0u, 0u, 0u};
    const uint32 mask = 0xFFFFFC00u;
#pragma unroll 2
    for (int g = 0; g < 64; ++g) {
        iv4 pa0 = afr_lds[(g * 2 + 0) * 64 + lane];
        iv4 pa1 = afr_lds[(g * 2 + 1) * 64 + lane];
        sv8 a0 = *(sv8*)&pa0;
        sv8 a1 = *(sv8*)&pa1;
        fv4 einit = *(const fv4*)(e2nl + g * 16 + q * 4);
        const uint32 invb = (uint32)(1023 - (g * 16 + q * 4));
#pragma unroll
        for (int j = 0; j < 4; ++j) {
            fv4 acc = __builtin_amdgcn_mfma_f32_16x16x32_bf16(a0, bfr[j][0], einit, 0, 0, 0);
            acc     = __builtin_amdgcn_mfma_f32_16x16x32_bf16(a1, bfr[j][1], acc,   0, 0, 0);
#pragma unroll
            for (int r = 0; r < 4; ++r)
                best[j] = umax(best[j],
                               (__float_as_uint(acc[r]) & mask) | (invb - (uint32)r));
        }
    }

    // ---- epilogue: finish argmax with 2 shfls per group, loss, gather, store
    float myloss = 0.0f;
#pragma unroll
    for (int j = 0; j < 4; ++j) {
        uint32 b = best[j];
        b = umax(b, (uint32)__shfl_xor((int)b, 16));
        b = umax(b, (uint32)__shfl_xor((int)b, 32));   // all 4 q-lanes have it
        const int id = 1023 - (int)(b & 1023u);
        if (q == 0) {
            const float sc = __uint_as_float(b & mask);
            myloss += zn[j] - 2.0f * (sc - 1.0f);
        }
        const int col = pxb + j * 16 + mcol;
        // gather: 4 q-lanes each fetch a quarter of the emb row (64 B)
#pragma unroll
        for (int jjj = 0; jjj < 4; ++jjj) {
            fv4 ev = ((const fv4*)embf)[id * 16 + q * 4 + jjj];
#pragma unroll
            for (int ee = 0; ee < 4; ++ee) {
                const int c = q * 16 + jjj * 4 + ee;
                out[zb + c * 4096 + col] = ev[ee];  // z + (z_q - z) == z_q
            }
        }
    }

    // ---- loss: wave butterfly (only q==0 lanes nonzero), then atomic
#pragma unroll
    for (int off = 1; off < 64; off <<= 1)
        myloss += __shfl_xor(myloss, off);
    if (lane == 0) lred[wv] = myloss;
    __syncthreads();
    if (tid == 0) {
        float s = 0.0f;
#pragma unroll
        for (int i = 0; i < 8; ++i) s += lred[i];
        atomicAdd(out + NELEM, s * (1.5f / (float)NELEM));
    }
}

extern "C" void kernel_launch(void* const* d_in, const int* in_sizes, int n_in,
                              void* d_out, int out_size, void* d_ws, size_t ws_size,
                              hipStream_t stream) {
    const float* z    = (const float*)d_in[0];
    const float* embf = (const float*)d_in[1];
    float* out        = (float*)d_out;

    iv4*   fragws = (iv4*)d_ws;                            // 128 KB
    float* e2n    = (float*)((char*)d_ws + 131072);        // 4 KB

    prep_kernel<<<dim3(16), dim3(256), 0, stream>>>(embf, fragws, e2n, out + NELEM);
    vq_kernel<<<dim3(NBLK), dim3(512), 0, stream>>>(z, embf, fragws, e2n, out);
}

// Round 11
// 105.329 us; speedup vs baseline: 1.0098x; 1.0098x over previous
//
#include <hip/hip_runtime.h>
#include <hip/hip_bf16.h>

// VectorQuantizer on MI355X — Round 18: vectorize z-loads & stores via
// per-wave LDS transpose (no new barriers).
// z: [32, 64, 64, 64] fp32 (B,C,H,W), emb: [1024, 64] fp32.
// out: z_q [32,64,64,64] fp32 (8388608) then loss (1 float).
//
// R17 post-mortem: halving main-loop LDS traffic was NEUTRAL -> main
// loop is not dominant. Untouched phases: z staging (32 scalar dword
// loads/lane) + out store (64 scalar dword stores/lane) — the G13
// violation. R1 counters: FETCH 17.5MB < z 33.5MB -> z is L3-resident,
// loads latency-bound -> fewer/wider instrs with more in flight.
// R18: per-wave transpose buffers (8 x 2.5KB, wave-private, DS ops
// wave-in-order => NO barriers): input (j,kc) chunk = 2x dwordx4
// (1KB/instr) -> LDS pad-18 (b64 writes, col reads 2-way=free) ->
// pack. Output per (j,half): 16 b32 LDS writes (2-way) + 2 b128 reads
// + 2 dwordx4 stores. Main loop / key-max / loss verbatim R17.
// Tells: LDS ~155.7KB, WRITE ~32.8MB (no spill), VGPR ~90.
// If neutral again: residual is outside vq -> declare roofline.

#define NELEM 8388608
#define NBLK  256

typedef short sv8 __attribute__((ext_vector_type(8)));
typedef float fv4 __attribute__((ext_vector_type(4)));
typedef int   iv4 __attribute__((ext_vector_type(4)));
typedef unsigned int uint32;

__device__ __forceinline__ uint32 pack2bf(float a, float b) {
    __hip_bfloat162 h = __float22bfloat162_rn(make_float2(a, b));
    union { __hip_bfloat162 h2; uint32 u; } cvt;
    cvt.h2 = h;
    return cvt.u;             // low 16 = a, high 16 = b
}

__device__ __forceinline__ uint32 umax(uint32 a, uint32 b) { return a > b ? a : b; }

// ---- prep: codebook -> bf16 A-frags (fragment order) + e2n = 1-0.5||e||^2.
//      Also zeroes the loss slot (stream-ordered before vq every replay).
__global__ __launch_bounds__(256) void prep_kernel(
        const float* __restrict__ embf,
        iv4* __restrict__ fragws,            // 8192 units of 16B
        float* __restrict__ e2n,             // 1024 floats
        float* __restrict__ out_loss) {
    if (blockIdx.x == 0 && threadIdx.x == 0) out_loss[0] = 0.0f;
    const int t = blockIdx.x * 256 + threadIdx.x;   // 0..4095
    const int g = t >> 6, l = t & 63;
    const int code = g * 16 + (l & 15);
    const int q    = l >> 4;
    float s2 = 0.0f;
#pragma unroll
    for (int kc = 0; kc < 2; ++kc) {
        fv4 u0 = ((const fv4*)embf)[code * 16 + kc * 8 + q * 2 + 0];
        fv4 u1 = ((const fv4*)embf)[code * 16 + kc * 8 + q * 2 + 1];
        s2 += u0[0]*u0[0] + u0[1]*u0[1] + u0[2]*u0[2] + u0[3]*u0[3]
            + u1[0]*u1[0] + u1[1]*u1[1] + u1[2]*u1[2] + u1[3]*u1[3];
        iv4 pv = { (int)pack2bf(u0[0], u0[1]), (int)pack2bf(u0[2], u0[3]),
                   (int)pack2bf(u1[0], u1[1]), (int)pack2bf(u1[2], u1[3]) };
        fragws[(g * 2 + kc) * 64 + l] = pv;
    }
    s2 += __shfl_xor(s2, 16);
    s2 += __shfl_xor(s2, 32);                // full ||e_code||^2
    if (q == 0) e2n[code] = 1.0f - 0.5f * s2;
}

__global__ __launch_bounds__(512, 2) void vq_kernel(
        const float* __restrict__ z,
        const float* __restrict__ embf,
        const iv4* __restrict__ fragws,
        const float* __restrict__ e2n,
        float* __restrict__ out) {
    __shared__ iv4   afr_lds[128 * 64];      // 128 KB  A-frags [g*2+kc][lane]
    __shared__ float e2nl[1024];             //   4 KB  1-0.5||e||^2
    __shared__ float lred[8];
    __shared__ __align__(16) float tbuf[8][640];  // 20 KB per-wave transpose

    const int tid   = threadIdx.x;
    const int blk   = blockIdx.x;
    const int batch = blk >> 3;
    const int hw0   = (blk & 7) << 9;        // 512 pixels per block
    const int zb    = batch * 262144;        // + c*4096 + px

    const int wv   = tid >> 6;               // 0..7
    const int lane = tid & 63;
    const int q    = lane >> 4;
    const int mcol = lane & 15;
    const int pxb  = hw0 + wv * 64;          // wave's 64 pixels
    const int cq   = lane >> 2;              // 0..15  c sub-index for vec ops
    const int px4  = (lane & 3) * 4;         // 0,4,8,12 pixel quad

    float* tb = tbuf[wv];

    // ---- phase 1: vectorized z load (dwordx4) + per-wave LDS transpose
    // (pad 18: b64 writes 8B-aligned; column reads 2-way = free).
    // DS ops are wave-in-order: chunk n reads complete before chunk n+1
    // writes; global loads of n+1 hoist above — no barriers needed.
    sv8   bfr[4][2];
    float zn[4];
#pragma unroll
    for (int j = 0; j < 4; ++j) {
        float sq = 0.0f;
#pragma unroll
        for (int kc = 0; kc < 2; ++kc) {
            const int gb = zb + pxb + j * 16 + px4;
            fv4 v0 = *(const fv4*)&z[gb + (kc * 32 +  0 + cq) * 4096];
            fv4 v1 = *(const fv4*)&z[gb + (kc * 32 + 16 + cq) * 4096];
            *(float2*)(tb + ( 0 + cq) * 18 + px4)     = make_float2(v0[0], v0[1]);
            *(float2*)(tb + ( 0 + cq) * 18 + px4 + 2) = make_float2(v0[2], v0[3]);
            *(float2*)(tb + (16 + cq) * 18 + px4)     = make_float2(v1[0], v1[1]);
            *(float2*)(tb + (16 + cq) * 18 + px4 + 2) = make_float2(v1[2], v1[3]);
            uint32 pk[4];
#pragma unroll
            for (int jj = 0; jj < 4; ++jj) {
                float f0 = tb[(q * 8 + jj * 2 + 0) * 18 + mcol];
                float f1 = tb[(q * 8 + jj * 2 + 1) * 18 + mcol];
                sq += f0 * f0 + f1 * f1;
                pk[jj] = pack2bf(f0, f1);
            }
            iv4 vv = { (int)pk[0], (int)pk[1], (int)pk[2], (int)pk[3] };
            bfr[j][kc] = *(sv8*)&vv;
        }
        sq += __shfl_xor(sq, 16);
        sq += __shfl_xor(sq, 32);            // full ||z_px||^2
        zn[j] = sq;
    }

    // ---- phase 2: stage codebook frags + e2n to LDS (L2-hot, coalesced)
#pragma unroll
    for (int i = 0; i < 16; ++i)
        afr_lds[i * 512 + tid] = fragws[i * 512 + tid];
    e2nl[tid]       = e2n[tid];
    e2nl[tid + 512] = e2n[tid + 512];
    __syncthreads();

    // ---- main loop: 64 code-groups, BARRIER-FREE, per-wave independent.
    uint32 best[4] = {0u, 0u, 0u, 0u};
    const uint32 mask = 0xFFFFFC00u;
#pragma unroll 2
    for (int g = 0; g < 64; ++g) {
        iv4 pa0 = afr_lds[(g * 2 + 0) * 64 + lane];
        iv4 pa1 = afr_lds[(g * 2 + 1) * 64 + lane];
        sv8 a0 = *(sv8*)&pa0;
        sv8 a1 = *(sv8*)&pa1;
        fv4 einit = *(const fv4*)(e2nl + g * 16 + q * 4);
        const uint32 invb = (uint32)(1023 - (g * 16 + q * 4));
#pragma unroll
        for (int j = 0; j < 4; ++j) {
            fv4 acc = __builtin_amdgcn_mfma_f32_16x16x32_bf16(a0, bfr[j][0], einit, 0, 0, 0);
            acc     = __builtin_amdgcn_mfma_f32_16x16x32_bf16(a1, bfr[j][1], acc,   0, 0, 0);
#pragma unroll
            for (int r = 0; r < 4; ++r)
                best[j] = umax(best[j],
                               (__float_as_uint(acc[r]) & mask) | (invb - (uint32)r));
        }
    }

    // ---- epilogue: argmax finish, loss, gather; vectorized store via
    // per-wave LDS transpose (pad 20: b32 writes 2-way; b128 reads).
    float myloss = 0.0f;
#pragma unroll
    for (int j = 0; j < 4; ++j) {
        uint32 b = best[j];
        b = umax(b, (uint32)__shfl_xor((int)b, 16));
        b = umax(b, (uint32)__shfl_xor((int)b, 32));   // all 4 q-lanes agree
        const int id = 1023 - (int)(b & 1023u);
        if (q == 0) {
            const float sc = __uint_as_float(b & mask);
            myloss += zn[j] - 2.0f * (sc - 1.0f);
        }
        fv4 ev[4];
#pragma unroll
        for (int jjj = 0; jjj < 4; ++jjj)
            ev[jjj] = ((const fv4*)embf)[id * 16 + q * 4 + jjj];
#pragma unroll
        for (int h = 0; h < 2; ++h) {
            // q=0,1 own c-half 0 (rows 0..31); q=2,3 own c-half 1
            if ((q >> 1) == h) {
#pragma unroll
                for (int jjj = 0; jjj < 4; ++jjj)
#pragma unroll
                    for (int ee = 0; ee < 4; ++ee)
                        tb[((q & 1) * 16 + jjj * 4 + ee) * 20 + mcol] = ev[jjj][ee];
            }
            // all lanes: 2 x (ds_read_b128 + global_store_dwordx4)
#pragma unroll
            for (int t = 0; t < 2; ++t) {
                const int row = t * 16 + cq;
                const int c   = h * 32 + row;
                fv4 sv = *(const fv4*)(tb + row * 20 + px4);
                *(fv4*)&out[zb + c * 4096 + pxb + j * 16 + px4] = sv;
            }
        }
    }

    // ---- loss: wave butterfly (only q==0 lanes nonzero), then atomic
#pragma unroll
    for (int off = 1; off < 64; off <<= 1)
        myloss += __shfl_xor(myloss, off);
    if (lane == 0) lred[wv] = myloss;
    __syncthreads();
    if (tid == 0) {
        float s = 0.0f;
#pragma unroll
        for (int i = 0; i < 8; ++i) s += lred[i];
        atomicAdd(out + NELEM, s * (1.5f / (float)NELEM));
    }
}

extern "C" void kernel_launch(void* const* d_in, const int* in_sizes, int n_in,
                              void* d_out, int out_size, void* d_ws, size_t ws_size,
                              hipStream_t stream) {
    const float* z    = (const float*)d_in[0];
    const float* embf = (const float*)d_in[1];
    float* out        = (float*)d_out;

    iv4*   fragws = (iv4*)d_ws;                            // 128 KB
    float* e2n    = (float*)((char*)d_ws + 131072);        // 4 KB

    prep_kernel<<<dim3(16), dim3(256), 0, stream>>>(embf, fragws, e2n, out + NELEM);
    vq_kernel<<<dim3(NBLK), dim3(512), 0, stream>>>(z, embf, fragws, e2n, out);
}